// Round 11
// baseline (176.926 us; speedup 1.0000x reference)
//
#include <hip/hip_runtime.h>
#include <hip/hip_fp16.h>

#define PTAB_STRIDE 64   // halves per row = 128 B

typedef float    f32x4 __attribute__((ext_vector_type(4)));
typedef _Float16 half8 __attribute__((ext_vector_type(8)));
typedef _Float16 h2    __attribute__((ext_vector_type(2)));

__device__ __forceinline__ h2 u2h2(unsigned int u) {
    union { unsigned int u; h2 h; } c; c.u = u; return c.h;
}

__device__ __forceinline__ float fdot2x(h2 a, h2 b, float c) {
#if __has_builtin(__builtin_amdgcn_fdot2)
    return __builtin_amdgcn_fdot2(a, b, c, false);
#else
    return c + (float)a[0] * (float)b[0] + (float)a[1] * (float)b[1];
#endif
}

// ---------------------------------------------------------------------------
// Kernel 0: pack B-fragments (W^T, fp16, zero-padded to K=320 x N=64) in the
// exact mfma_f32_16x16x32_f16 per-lane layout, + fused bias table.
// ---------------------------------------------------------------------------
__global__ __launch_bounds__(64) void prep_kernel(
    const float* __restrict__ Wih, const float* __restrict__ bih,
    const float* __restrict__ bhh, __half* __restrict__ Bfrag,
    float* __restrict__ bias64)
{
    const int lane = threadIdx.x;
    const int st   = blockIdx.x;
    if (st == 40) {
        if (lane < 64) bias64[lane] = (lane < 50) ? bih[lane] + bhh[lane] : 0.f;
        return;
    }
    const int s  = st >> 2, t = st & 3;
    const int n  = 16 * t + (lane & 15);
    const int kb = lane >> 4;
    half8 v;
    #pragma unroll
    for (int j = 0; j < 8; ++j) {
        const int k = 32 * s + 8 * kb + j;
        float w = 0.f;
        if (n < 50 && k < 300) w = Wih[n * 300 + k];
        v[j] = (_Float16)w;
    }
    *reinterpret_cast<half8*>(Bfrag + ((size_t)st * 64 + lane) * 8) = v;
}

// ---------------------------------------------------------------------------
// Phase 1: ptab[v][h] = fp16( dot(emb[v,:], W_ih[h,:]) + b_ih + b_hh )
// One wave per 16 vocab rows, 4 N-tile accumulators, 40 MFMAs. (proven)
// ---------------------------------------------------------------------------
__global__ __launch_bounds__(64) void ptab_mfma(
    const float* __restrict__ emb, const __half* __restrict__ Bfrag,
    const float* __restrict__ bias64, __half* __restrict__ ptab)
{
    const int lane = threadIdx.x;
    const int v0   = blockIdx.x * 16;
    const int m    = lane & 15;
    const int kb   = lane >> 4;
    const float* Erow = emb + (size_t)(v0 + m) * 300;
    const half8* BF   = reinterpret_cast<const half8*>(Bfrag);

    f32x4 acc[4];
    #pragma unroll
    for (int t = 0; t < 4; ++t) acc[t] = (f32x4){0.f, 0.f, 0.f, 0.f};

    #pragma unroll
    for (int s = 0; s < 9; ++s) {
        const int k0 = 32 * s + 8 * kb;
        float4 p0 = *(const float4*)(Erow + k0);
        float4 p1 = *(const float4*)(Erow + k0 + 4);
        half8 a;
        a[0] = (_Float16)p0.x; a[1] = (_Float16)p0.y;
        a[2] = (_Float16)p0.z; a[3] = (_Float16)p0.w;
        a[4] = (_Float16)p1.x; a[5] = (_Float16)p1.y;
        a[6] = (_Float16)p1.z; a[7] = (_Float16)p1.w;
        #pragma unroll
        for (int t = 0; t < 4; ++t)
            acc[t] = __builtin_amdgcn_mfma_f32_16x16x32_f16(
                a, BF[(4 * s + t) * 64 + lane], acc[t], 0, 0, 0);
    }
    {   // tail K-step s=9: k = 288..319, valid only k < 300
        half8 a;
        #pragma unroll
        for (int j = 0; j < 8; ++j) {
            const int k = 288 + 8 * kb + j;
            float e = 0.f;
            if (k < 300) e = Erow[k];
            a[j] = (_Float16)e;
        }
        #pragma unroll
        for (int t = 0; t < 4; ++t)
            acc[t] = __builtin_amdgcn_mfma_f32_16x16x32_f16(
                a, BF[(36 + t) * 64 + lane], acc[t], 0, 0, 0);
    }

    const int nn = lane & 15;
    #pragma unroll
    for (int t = 0; t < 4; ++t) {
        const float bt = bias64[16 * t + nn];
        #pragma unroll
        for (int r = 0; r < 4; ++r)
            ptab[(size_t)(v0 + 4 * kb + r) * PTAB_STRIDE + 16 * t + nn] =
                (__half)(acc[t][r] + bt);
    }
}

// ---------------------------------------------------------------------------
// Phase 2: recurrence + head. TWO sequences per wave, 128 waves.
// Per step-pair: 2 ds_write_b16 + 12 uniform-broadcast ds_read (all 14 DS
// ops pipeline in-order through the DS unit; seq B's dots fill seq A's DS
// wait) + 50 v_dot2_f32_f16 in 4 chains + 2 tanh. W_hh (25 packed fp16
// pairs, shared by both seqs) is re-pinned to VGPRs with empty asm "+v"
// INSIDE the loop so the allocator cannot spill/remat it (r8 lesson:
// init-time-only pinning left VGPR=48 and W was reloaded every step).
// x gathers prefetched 8 steps ahead per sequence. Biases folded into ptab.
// ---------------------------------------------------------------------------
__global__ __launch_bounds__(64, 1) void rnn_kernel(
    const int* __restrict__ tokens, const __half* __restrict__ ptab,
    const float* __restrict__ Whh,
    const float* __restrict__ Wfc, const float* __restrict__ bfc,
    float* __restrict__ out)
{
    __shared__ int stokA[544], stokB[544];
    __shared__ __align__(16) _Float16 hbufA[64];
    __shared__ __align__(16) _Float16 hbufB[64];
    const int lane = threadIdx.x;
    const int bA   = blockIdx.x * 2;
    const int bB   = bA + 1;
    const int hc   = lane < 50 ? lane : 49;

    #pragma unroll
    for (int k = 0; k < 8; ++k) {
        stokA[lane + 64 * k] = tokens[bA * 512 + lane + 64 * k];
        stokB[lane + 64 * k] = tokens[bB * 512 + lane + 64 * k];
    }
    if (lane < 32) { stokA[512 + lane] = 0; stokB[512 + lane] = 0; }
    __syncthreads();

    // W_hh row for this lane: 25 packed fp16 pairs.
    unsigned int wh_u[25];
    #pragma unroll
    for (int j = 0; j < 25; ++j) {
        float2 w2 = *(const float2*)(Whh + hc * 50 + 2 * j);
        union { h2 h; unsigned int u; } c;
        c.h = (h2){(_Float16)w2.x, (_Float16)w2.y};
        wh_u[j] = c.u;
    }

    float hA = 0.f, hB = 0.f;

#define GA(T) ptab[(size_t)(T) * PTAB_STRIDE + lane]

    __half xA0 = GA(stokA[0]), xA1 = GA(stokA[1]), xA2 = GA(stokA[2]), xA3 = GA(stokA[3]);
    __half xA4 = GA(stokA[4]), xA5 = GA(stokA[5]), xA6 = GA(stokA[6]), xA7 = GA(stokA[7]);
    __half xB0 = GA(stokB[0]), xB1 = GA(stokB[1]), xB2 = GA(stokB[2]), xB3 = GA(stokB[3]);
    __half xB4 = GA(stokB[4]), xB5 = GA(stokB[5]), xB6 = GA(stokB[6]), xB7 = GA(stokB[7]);
    int kA0 = stokA[8],  kA1 = stokA[9],  kA2 = stokA[10], kA3 = stokA[11];
    int kA4 = stokA[12], kA5 = stokA[13], kA6 = stokA[14], kA7 = stokA[15];
    int kB0 = stokB[8],  kB1 = stokB[9],  kB2 = stokB[10], kB3 = stokB[11];
    int kB4 = stokB[12], kB5 = stokB[13], kB6 = stokB[14], kB7 = stokB[15];

#define SL(Q, i) __builtin_shufflevector(Q, Q, 2*(i), 2*(i)+1)
#define WH(j) u2h2(wh_u[j])

#define DOTQ(S0, S1, q0, q1, q2, q3, q4, q5, q6)                              \
        S0 = fdot2x(SL(q0,0), WH(0),  S0); S1 = fdot2x(SL(q0,1), WH(1),  S1); \
        S0 = fdot2x(SL(q0,2), WH(2),  S0); S1 = fdot2x(SL(q0,3), WH(3),  S1); \
        S0 = fdot2x(SL(q1,0), WH(4),  S0); S1 = fdot2x(SL(q1,1), WH(5),  S1); \
        S0 = fdot2x(SL(q1,2), WH(6),  S0); S1 = fdot2x(SL(q1,3), WH(7),  S1); \
        S0 = fdot2x(SL(q2,0), WH(8),  S0); S1 = fdot2x(SL(q2,1), WH(9),  S1); \
        S0 = fdot2x(SL(q2,2), WH(10), S0); S1 = fdot2x(SL(q2,3), WH(11), S1); \
        S0 = fdot2x(SL(q3,0), WH(12), S0); S1 = fdot2x(SL(q3,1), WH(13), S1); \
        S0 = fdot2x(SL(q3,2), WH(14), S0); S1 = fdot2x(SL(q3,3), WH(15), S1); \
        S0 = fdot2x(SL(q4,0), WH(16), S0); S1 = fdot2x(SL(q4,1), WH(17), S1); \
        S0 = fdot2x(SL(q4,2), WH(18), S0); S1 = fdot2x(SL(q4,3), WH(19), S1); \
        S0 = fdot2x(SL(q5,0), WH(20), S0); S1 = fdot2x(SL(q5,1), WH(21), S1); \
        S0 = fdot2x(SL(q5,2), WH(22), S0); S1 = fdot2x(SL(q5,3), WH(23), S1); \
        S0 = fdot2x(q6,       WH(24), S0);

#define TANHS(H, XV, S0, S1)                                              \
    {                                                                     \
        float a = (float)(XV) + (S0 + S1);                                \
        a = fminf(9.f, fmaxf(-9.f, a));                                   \
        float e = __expf(2.f * a);                                        \
        H = fmaf(-2.f, __builtin_amdgcn_rcpf(e + 1.f), 1.f);              \
    }

#define STEP2(XA, XB)                                                     \
    {                                                                     \
        hbufA[lane] = (_Float16)hA;        /* ds_write_b16 */             \
        hbufB[lane] = (_Float16)hB;        /* ds_write_b16 */             \
        const half8* HA8 = (const half8*)hbufA;                           \
        const half8* HB8 = (const half8*)hbufB;                           \
        half8 qa0 = HA8[0], qa1 = HA8[1], qa2 = HA8[2];                   \
        half8 qa3 = HA8[3], qa4 = HA8[4], qa5 = HA8[5];                   \
        h2 qa6 = *(const h2*)(hbufA + 48);                                \
        half8 qb0 = HB8[0], qb1 = HB8[1], qb2 = HB8[2];                   \
        half8 qb3 = HB8[3], qb4 = HB8[4], qb5 = HB8[5];                   \
        h2 qb6 = *(const h2*)(hbufB + 48);                                \
        float sA0 = 0.f, sA1 = 0.f, sB0 = 0.f, sB1 = 0.f;                 \
        DOTQ(sA0, sA1, qa0, qa1, qa2, qa3, qa4, qa5, qa6)                 \
        DOTQ(sB0, sB1, qb0, qb1, qb2, qb3, qb4, qb5, qb6)                 \
        TANHS(hA, XA, sA0, sA1)                                           \
        TANHS(hB, XB, sB0, sB1)                                           \
    }

    for (int t = 0; t < 512; t += 8) {
        // keep W_hh pinned: empty asm def-use each iteration (no code emitted)
        #pragma unroll
        for (int j = 0; j < 25; ++j) asm volatile("" : "+v"(wh_u[j]));

        __half nA0 = GA(kA0), nA1 = GA(kA1), nA2 = GA(kA2), nA3 = GA(kA3);
        __half nA4 = GA(kA4), nA5 = GA(kA5), nA6 = GA(kA6), nA7 = GA(kA7);
        __half nB0 = GA(kB0), nB1 = GA(kB1), nB2 = GA(kB2), nB3 = GA(kB3);
        __half nB4 = GA(kB4), nB5 = GA(kB5), nB6 = GA(kB6), nB7 = GA(kB7);
        kA0 = stokA[t + 16]; kA1 = stokA[t + 17]; kA2 = stokA[t + 18]; kA3 = stokA[t + 19];
        kA4 = stokA[t + 20]; kA5 = stokA[t + 21]; kA6 = stokA[t + 22]; kA7 = stokA[t + 23];
        kB0 = stokB[t + 16]; kB1 = stokB[t + 17]; kB2 = stokB[t + 18]; kB3 = stokB[t + 19];
        kB4 = stokB[t + 20]; kB5 = stokB[t + 21]; kB6 = stokB[t + 22]; kB7 = stokB[t + 23];

        STEP2(xA0, xB0); STEP2(xA1, xB1); STEP2(xA2, xB2); STEP2(xA3, xB3);
        STEP2(xA4, xB4); STEP2(xA5, xB5); STEP2(xA6, xB6); STEP2(xA7, xB7);

        xA0 = nA0; xA1 = nA1; xA2 = nA2; xA3 = nA3;
        xA4 = nA4; xA5 = nA5; xA6 = nA6; xA7 = nA7;
        xB0 = nB0; xB1 = nB1; xB2 = nB2; xB3 = nB3;
        xB4 = nB4; xB5 = nB5; xB6 = nB6; xB7 = nB7;
    }
#undef STEP2
#undef TANHS
#undef DOTQ
#undef SL
#undef WH
#undef GA

    // ---- head: out[b][o] = sum_h h[h] * W_fc[o][h] + b_fc[o], both seqs ----
    float hvA = (lane < 50) ? hA : 0.f;
    float hvB = (lane < 50) ? hB : 0.f;
    #pragma unroll
    for (int o = 0; o < 4; ++o) {
        float w  = (lane < 50) ? Wfc[o * 50 + lane] : 0.f;
        float pA = hvA * w;
        float pB = hvB * w;
        #pragma unroll
        for (int s = 32; s > 0; s >>= 1) {
            pA += __shfl_xor(pA, s, 64);
            pB += __shfl_xor(pB, s, 64);
        }
        if (lane == 0) {
            out[bA * 4 + o] = pA + bfc[o];
            out[bB * 4 + o] = pB + bfc[o];
        }
    }
}

extern "C" void kernel_launch(void* const* d_in, const int* in_sizes, int n_in,
                              void* d_out, int out_size, void* d_ws, size_t ws_size,
                              hipStream_t stream)
{
    const int*   tokens = (const int*)d_in[0];
    const float* emb    = (const float*)d_in[1];
    const float* Wih    = (const float*)d_in[2];
    const float* Whh    = (const float*)d_in[3];
    const float* bih    = (const float*)d_in[4];
    const float* bhh    = (const float*)d_in[5];
    const float* Wfc    = (const float*)d_in[6];
    const float* bfc    = (const float*)d_in[7];

    char* ws = (char*)d_ws;
    __half* ptab   = (__half*)ws;                       // 6,400,000 B
    __half* Bfrag  = (__half*)(ws + 6400000);           //    40,960 B
    float*  bias64 = (float*)(ws + 6440960);            //       256 B
    float*  outp   = (float*)d_out;

    prep_kernel<<<41, 64, 0, stream>>>(Wih, bih, bhh, Bfrag, bias64);
    ptab_mfma<<<3125, 64, 0, stream>>>(emb, Bfrag, bias64, ptab);
    rnn_kernel<<<128, 64, 0, stream>>>(tokens, ptab, Whh, Wfc, bfc, outp);
}

// Round 12
// 131.273 us; speedup vs baseline: 1.3478x; 1.3478x over previous
//
#include <hip/hip_runtime.h>
#include <hip/hip_fp16.h>

#define PTAB_STRIDE 64   // halves per row = 128 B

typedef float    f32x4 __attribute__((ext_vector_type(4)));
typedef _Float16 half8 __attribute__((ext_vector_type(8)));
typedef _Float16 h2    __attribute__((ext_vector_type(2)));

__device__ __forceinline__ h2 u2h2(unsigned int u) {
    union { unsigned int u; h2 h; } c; c.u = u; return c.h;
}

__device__ __forceinline__ float fdot2x(h2 a, h2 b, float c) {
#if __has_builtin(__builtin_amdgcn_fdot2)
    return __builtin_amdgcn_fdot2(a, b, c, false);
#else
    return c + (float)a[0] * (float)b[0] + (float)a[1] * (float)b[1];
#endif
}

#if __has_builtin(__builtin_amdgcn_permlane16_swap)
#define HAVE_PL16 1
#else
#define HAVE_PL16 0
#endif
#if __has_builtin(__builtin_amdgcn_permlane32_swap)
#define HAVE_PL32 1
#else
#define HAVE_PL32 0
#endif

// DPP permute (VALU pipe). ctrl: 0xB1=quad xor1, 0x4E=quad xor2,
// 0x141=row_half_mirror (xor7), 0x140=row_mirror (xor15).
#define DPPX(v, ctrl) \
    ((unsigned)__builtin_amdgcn_update_dpp(0, (int)(v), (ctrl), 0xf, 0xf, true))

// xor16 exchange: A = (lane&16 ? foreign : own), B = complementary (native);
// fallback: A = own, B = foreign for all lanes.
__device__ __forceinline__ void xsw16(unsigned p, unsigned &A, unsigned &B) {
#if HAVE_PL16
    auto rr = __builtin_amdgcn_permlane16_swap(p, p, false, false);
    A = (unsigned)rr[0]; B = (unsigned)rr[1];
#else
    A = p;
    B = (unsigned)__builtin_amdgcn_ds_swizzle((int)p, 0x401F);  // xor16
#endif
}

// xor32 exchange: P = (lane&32 ? foreign : own), Q = complementary (native);
// fallback: P = own, Q = foreign.
__device__ __forceinline__ void xsw32(unsigned x, unsigned &P, unsigned &Q) {
#if HAVE_PL32
    auto rr = __builtin_amdgcn_permlane32_swap(x, x, false, false);
    P = (unsigned)rr[0]; Q = (unsigned)rr[1];
#else
    P = x;
    Q = (unsigned)__builtin_amdgcn_ds_bpermute(
            (int)(((threadIdx.x ^ 32) & 63) << 2), (int)x);
#endif
}

// ---------------------------------------------------------------------------
// Kernel 0: pack B-fragments (W^T, fp16, zero-padded to K=320 x N=64) in the
// exact mfma_f32_16x16x32_f16 per-lane layout, + fused bias table.
// ---------------------------------------------------------------------------
__global__ __launch_bounds__(64) void prep_kernel(
    const float* __restrict__ Wih, const float* __restrict__ bih,
    const float* __restrict__ bhh, __half* __restrict__ Bfrag,
    float* __restrict__ bias64)
{
    const int lane = threadIdx.x;
    const int st   = blockIdx.x;
    if (st == 40) {
        if (lane < 64) bias64[lane] = (lane < 50) ? bih[lane] + bhh[lane] : 0.f;
        return;
    }
    const int s  = st >> 2, t = st & 3;
    const int n  = 16 * t + (lane & 15);
    const int kb = lane >> 4;
    half8 v;
    #pragma unroll
    for (int j = 0; j < 8; ++j) {
        const int k = 32 * s + 8 * kb + j;
        float w = 0.f;
        if (n < 50 && k < 300) w = Wih[n * 300 + k];
        v[j] = (_Float16)w;
    }
    *reinterpret_cast<half8*>(Bfrag + ((size_t)st * 64 + lane) * 8) = v;
}

// ---------------------------------------------------------------------------
// Phase 1: ptab[v][h] = fp16( dot(emb[v,:], W_ih[h,:]) + b_ih + b_hh )
// One wave per 16 vocab rows, 4 N-tile accumulators, 40 MFMAs. (proven)
// ---------------------------------------------------------------------------
__global__ __launch_bounds__(64) void ptab_mfma(
    const float* __restrict__ emb, const __half* __restrict__ Bfrag,
    const float* __restrict__ bias64, __half* __restrict__ ptab)
{
    const int lane = threadIdx.x;
    const int v0   = blockIdx.x * 16;
    const int m    = lane & 15;
    const int kb   = lane >> 4;
    const float* Erow = emb + (size_t)(v0 + m) * 300;
    const half8* BF   = reinterpret_cast<const half8*>(Bfrag);

    f32x4 acc[4];
    #pragma unroll
    for (int t = 0; t < 4; ++t) acc[t] = (f32x4){0.f, 0.f, 0.f, 0.f};

    #pragma unroll
    for (int s = 0; s < 9; ++s) {
        const int k0 = 32 * s + 8 * kb;
        float4 p0 = *(const float4*)(Erow + k0);
        float4 p1 = *(const float4*)(Erow + k0 + 4);
        half8 a;
        a[0] = (_Float16)p0.x; a[1] = (_Float16)p0.y;
        a[2] = (_Float16)p0.z; a[3] = (_Float16)p0.w;
        a[4] = (_Float16)p1.x; a[5] = (_Float16)p1.y;
        a[6] = (_Float16)p1.z; a[7] = (_Float16)p1.w;
        #pragma unroll
        for (int t = 0; t < 4; ++t)
            acc[t] = __builtin_amdgcn_mfma_f32_16x16x32_f16(
                a, BF[(4 * s + t) * 64 + lane], acc[t], 0, 0, 0);
    }
    {   // tail K-step s=9: k = 288..319, valid only k < 300
        half8 a;
        #pragma unroll
        for (int j = 0; j < 8; ++j) {
            const int k = 288 + 8 * kb + j;
            float e = 0.f;
            if (k < 300) e = Erow[k];
            a[j] = (_Float16)e;
        }
        #pragma unroll
        for (int t = 0; t < 4; ++t)
            acc[t] = __builtin_amdgcn_mfma_f32_16x16x32_f16(
                a, BF[(36 + t) * 64 + lane], acc[t], 0, 0, 0);
    }

    const int nn = lane & 15;
    #pragma unroll
    for (int t = 0; t < 4; ++t) {
        const float bt = bias64[16 * t + nn];
        #pragma unroll
        for (int r = 0; r < 4; ++r)
            ptab[(size_t)(v0 + 4 * kb + r) * PTAB_STRIDE + 16 * t + nn] =
                (__half)(acc[t][r] + bt);
    }
}

// ---------------------------------------------------------------------------
// Phase 2: recurrence + head. One sequence per wave, 256 waves (1/CU).
// VALU-only xor all-gather for h (validated in r10): pack(xor1 DPP) ->
// permlane16_swap (xor16) -> permlane32_swap (xor32) -> DPP xor2 ->
// DPP xor7 -> DPP xor15. Lane's 32 dwords hold h[l^d^e^m]; W_hh pre-packed
// per-lane in exactly that order, so the dot is 32 order-invariant
// v_dot2_f32_f16.
// KEY CHANGE vs r10: amdgpu_waves_per_eu(1,1) unlocks the VGPR budget
// (r8/r10/r11 all spilled W at VGPR=44-48 because the allocator targeted
// high occupancy; the 32 wpk words + ~32 gather transients need ~110 regs).
// Verification signal: VGPR_Count must be >=100 this round.
// ---------------------------------------------------------------------------
__global__ __launch_bounds__(64, 1)
__attribute__((amdgpu_waves_per_eu(1, 1)))
void rnn_kernel(
    const int* __restrict__ tokens, const __half* __restrict__ ptab,
    const float* __restrict__ Whh,
    const float* __restrict__ Wfc, const float* __restrict__ bfc,
    float* __restrict__ out)
{
    __shared__ int stok[544];
    const int lane = threadIdx.x;
    const int b    = blockIdx.x;

    #pragma unroll
    for (int k = 0; k < 8; ++k)
        stok[lane + 64 * k] = tokens[b * 512 + lane + 64 * k];
    if (lane < 32) stok[512 + lane] = 0;     // pad: token 0 -> valid row
    __syncthreads();

    // per-lane slot->h-index masks (depend on which swap path compiled in)
    const int mA16 = HAVE_PL16 ? ((lane & 16) ? 16 : 0) : 0;
    const int mB16 = HAVE_PL16 ? ((lane & 16) ? 0 : 16) : 16;
    const int aP32 = HAVE_PL32 ? ((lane & 32) ? 32 : 0) : 0;
    const int aQ32 = HAVE_PL32 ? ((lane & 32) ? 0 : 32) : 32;
    const int mfam[4] = {mA16 | aP32, mA16 | aQ32, mB16 | aP32, mB16 | aQ32};
    const int dlt[8]  = {0, 2, 7, 5, 15, 13, 8, 10};

    // W_hh row of this lane, packed in gather order, pinned in VGPRs.
    unsigned wpk[8][4];
    #pragma unroll
    for (int di = 0; di < 8; ++di) {
        #pragma unroll
        for (int f = 0; f < 4; ++f) {
            const int ka = lane ^ dlt[di] ^ mfam[f];
            const int kb = ka ^ 1;
            _Float16 wa = (lane < 50 && ka < 50)
                              ? (_Float16)Whh[lane * 50 + ka] : (_Float16)0.f;
            _Float16 wb = (lane < 50 && kb < 50)
                              ? (_Float16)Whh[lane * 50 + kb] : (_Float16)0.f;
            union { h2 h; unsigned u; } c;
            c.h = (h2){wa, wb};
            wpk[di][f] = c.u;
        }
    }

    float h = 0.f;

#define GA(T) ptab[(size_t)(T) * PTAB_STRIDE + lane]

    __half x0 = GA(stok[0]), x1 = GA(stok[1]), x2 = GA(stok[2]), x3 = GA(stok[3]);
    __half x4 = GA(stok[4]), x5 = GA(stok[5]), x6 = GA(stok[6]), x7 = GA(stok[7]);
    int k0 = stok[8],  k1 = stok[9],  k2 = stok[10], k3 = stok[11];
    int k4 = stok[12], k5 = stok[13], k6 = stok[14], k7 = stok[15];

#define RNN_STEP(XV)                                                         \
    {                                                                        \
        union { _Float16 hf; unsigned short us; } hcv;                       \
        hcv.hf = (_Float16)h;                                                \
        unsigned hh = hcv.us;                                                \
        unsigned nb = DPPX(hh, 0xB1);            /* xor1 */                  \
        unsigned p  = hh | (nb << 16);                                       \
        unsigned A, B;                                                       \
        xsw16(p, A, B);                          /* xor16 */                 \
        unsigned g[8][4];                                                    \
        xsw32(A, g[0][0], g[0][1]);              /* xor32 */                 \
        xsw32(B, g[0][2], g[0][3]);                                          \
        _Pragma("unroll")                                                    \
        for (int f = 0; f < 4; ++f)                                          \
            g[1][f] = DPPX(g[0][f], 0x4E);       /* xor2 */                  \
        _Pragma("unroll")                                                    \
        for (int f = 0; f < 4; ++f) {                                        \
            g[2][f] = DPPX(g[0][f], 0x141);      /* xor7 */                  \
            g[3][f] = DPPX(g[1][f], 0x141);                                  \
        }                                                                    \
        _Pragma("unroll")                                                    \
        for (int f = 0; f < 4; ++f) {                                        \
            g[4][f] = DPPX(g[0][f], 0x140);      /* xor15 */                 \
            g[5][f] = DPPX(g[1][f], 0x140);                                  \
            g[6][f] = DPPX(g[2][f], 0x140);                                  \
            g[7][f] = DPPX(g[3][f], 0x140);                                  \
        }                                                                    \
        float s[4] = {0.f, 0.f, 0.f, 0.f};                                   \
        _Pragma("unroll")                                                    \
        for (int di = 0; di < 8; ++di) {                                     \
            _Pragma("unroll")                                                \
            for (int f = 0; f < 4; ++f)                                      \
                s[f] = fdot2x(u2h2(g[di][f]), u2h2(wpk[di][f]), s[f]);       \
        }                                                                    \
        float a = (float)(XV) + ((s[0] + s[1]) + (s[2] + s[3]));             \
        a = fminf(9.f, fmaxf(-9.f, a));                                      \
        float e = __expf(2.f * a);                                           \
        h = fmaf(-2.f, __builtin_amdgcn_rcpf(e + 1.f), 1.f);                 \
    }

    for (int t = 0; t < 512; t += 8) {
        // keep W packed words resident: cost-free def-use each iteration
        #pragma unroll
        for (int di = 0; di < 8; ++di)
            #pragma unroll
            for (int f = 0; f < 4; ++f)
                asm volatile("" : "+v"(wpk[di][f]));

        __half n0 = GA(k0), n1 = GA(k1), n2 = GA(k2), n3 = GA(k3);
        __half n4 = GA(k4), n5 = GA(k5), n6 = GA(k6), n7 = GA(k7);
        k0 = stok[t + 16]; k1 = stok[t + 17]; k2 = stok[t + 18]; k3 = stok[t + 19];
        k4 = stok[t + 20]; k5 = stok[t + 21]; k6 = stok[t + 22]; k7 = stok[t + 23];

        RNN_STEP(x0); RNN_STEP(x1); RNN_STEP(x2); RNN_STEP(x3);
        RNN_STEP(x4); RNN_STEP(x5); RNN_STEP(x6); RNN_STEP(x7);

        x0 = n0; x1 = n1; x2 = n2; x3 = n3;
        x4 = n4; x5 = n5; x6 = n6; x7 = n7;
    }
#undef RNN_STEP
#undef GA

    // ---- head: out[b][o] = sum_h h[h] * W_fc[o][h] + b_fc[o] ----
    float hv = (lane < 50) ? h : 0.f;
    #pragma unroll
    for (int o = 0; o < 4; ++o) {
        float w = (lane < 50) ? Wfc[o * 50 + lane] : 0.f;
        float p = hv * w;
        #pragma unroll
        for (int s = 32; s > 0; s >>= 1) p += __shfl_xor(p, s, 64);
        if (lane == 0) out[b * 4 + o] = p + bfc[o];
    }
}

extern "C" void kernel_launch(void* const* d_in, const int* in_sizes, int n_in,
                              void* d_out, int out_size, void* d_ws, size_t ws_size,
                              hipStream_t stream)
{
    const int*   tokens = (const int*)d_in[0];
    const float* emb    = (const float*)d_in[1];
    const float* Wih    = (const float*)d_in[2];
    const float* Whh    = (const float*)d_in[3];
    const float* bih    = (const float*)d_in[4];
    const float* bhh    = (const float*)d_in[5];
    const float* Wfc    = (const float*)d_in[6];
    const float* bfc    = (const float*)d_in[7];

    char* ws = (char*)d_ws;
    __half* ptab   = (__half*)ws;                       // 6,400,000 B
    __half* Bfrag  = (__half*)(ws + 6400000);           //    40,960 B
    float*  bias64 = (float*)(ws + 6440960);            //       256 B
    float*  outp   = (float*)d_out;

    prep_kernel<<<41, 64, 0, stream>>>(Wih, bih, bhh, Bfrag, bias64);
    ptab_mfma<<<3125, 64, 0, stream>>>(emb, Bfrag, bias64, ptab);
    rnn_kernel<<<256, 64, 0, stream>>>(tokens, ptab, Whh, Wfc, bfc, outp);
}